// Round 1
// baseline (128.926 us; speedup 1.0000x reference)
//
#include <hip/hip_runtime.h>

#define SEQ   8192
#define EMB   64
#define NLEAF 8192
#define KQ    2048          // K per gemm block (quarter of SEQ)
#define KT    64            // K per LDS tile
#define NT    (KQ / KT)     // 32 tiles

typedef __attribute__((ext_vector_type(4))) float        f32x4;
typedef __attribute__((ext_vector_type(4))) unsigned int u32x4;

// ---- bf16 split helpers (truncation; residual ~2^-16 relative) ----
__device__ __forceinline__ unsigned pack2(float x, float y) {
    return (__float_as_uint(x) >> 16) | (__float_as_uint(y) & 0xffff0000u);
}
__device__ __forceinline__ float bftrunc(float x) {
    return __uint_as_float(__float_as_uint(x) & 0xffff0000u);
}

__device__ __forceinline__ void mfma16(f32x4& d, const u32x4 a, const u32x4 b) {
    asm("v_mfma_f32_16x16x32_bf16 %0, %1, %2, %0" : "+v"(d) : "v"(a), "v"(b));
}

// Read 8 consecutive-k f32 from a swizzled 64x64 f32 LDS tile (256B rows,
// 16B chunk index XORed with row&7), emit hi/lo bf16 fragments (packed pairs).
__device__ __forceinline__ void frag_cvt(const float* buf, int row, int kk,
                                         u32x4& hi, u32x4& lo) {
    const int c = kk >> 2;          // even chunk index
    const int s = row & 7;
    const char* base = (const char*)buf + row * 256;
    const f32x4 v0 = *(const f32x4*)(base + 16 * (c ^ s));
    const f32x4 v1 = *(const f32x4*)(base + 16 * ((c + 1) ^ s));
    u32x4 h, l;
    h[0] = pack2(v0.x, v0.y);
    h[1] = pack2(v0.z, v0.w);
    h[2] = pack2(v1.x, v1.y);
    h[3] = pack2(v1.z, v1.w);
    l[0] = pack2(v0.x - bftrunc(v0.x), v0.y - bftrunc(v0.y));
    l[1] = pack2(v0.z - bftrunc(v0.z), v0.w - bftrunc(v0.w));
    l[2] = pack2(v1.x - bftrunc(v1.x), v1.y - bftrunc(v1.y));
    l[3] = pack2(v1.z - bftrunc(v1.z), v1.w - bftrunc(v1.w));
    hi = h; lo = l;
}

// ============================================================================
// K1: leaf embedding GEMM, split-bf16 MFMA, K-quarter partials (no bias/relu).
// grid 512 = 128 leaf-groups x 4 k-quarters; block 256; LDS 64KB; 2 blocks/CU.
// ============================================================================
__global__ __launch_bounds__(256, 2) void k_gemm(
        const float* __restrict__ A, const float* __restrict__ W,
        float* __restrict__ P)
{
    __shared__ float sA[2][64 * 64];
    __shared__ float sW[2][64 * 64];

    const int tid  = threadIdx.x;
    const int lane = tid & 63;
    const int wid  = tid >> 6;

    const int g     = blockIdx.x >> 2;   // leaf group (64 leaves)
    const int q     = blockIdx.x & 3;    // k quarter
    const int gl0   = g * 64;
    const int kbase = q * KQ;

    // ---- staging map: thread -> (row sr, 64B col-chunk sq) of both tiles ----
    const int sr = tid & 63;
    const int sq = tid >> 6;
    const float* srcA = A + (size_t)(gl0 + sr) * SEQ + kbase + sq * 16;
    const float* srcW = W + (size_t)sr * SEQ + kbase + sq * 16;
    const int wb0 = sr * 256 + 16 * (((sq * 4) + 0) ^ (sr & 7));
    const int wb1 = sr * 256 + 16 * (((sq * 4) + 1) ^ (sr & 7));
    const int wb2 = sr * 256 + 16 * (((sq * 4) + 2) ^ (sr & 7));
    const int wb3 = sr * 256 + 16 * (((sq * 4) + 3) ^ (sr & 7));

    // ---- per-wave output tiles: wave -> (m-pair, n-pair) of 16x16 tiles ----
    const int mt0 = (wid & 1) * 2;
    const int nt0 = (wid >> 1) * 2;
    const int fr  = lane & 15;
    const int fk  = (lane >> 4) * 8;

    f32x4 acc00 = {0.f, 0.f, 0.f, 0.f};
    f32x4 acc01 = {0.f, 0.f, 0.f, 0.f};
    f32x4 acc10 = {0.f, 0.f, 0.f, 0.f};
    f32x4 acc11 = {0.f, 0.f, 0.f, 0.f};

    // prologue: stage tile 0
    {
        const f32x4 a0 = *(const f32x4*)(srcA);
        const f32x4 a1 = *(const f32x4*)(srcA + 4);
        const f32x4 a2 = *(const f32x4*)(srcA + 8);
        const f32x4 a3 = *(const f32x4*)(srcA + 12);
        const f32x4 w0 = *(const f32x4*)(srcW);
        const f32x4 w1 = *(const f32x4*)(srcW + 4);
        const f32x4 w2 = *(const f32x4*)(srcW + 8);
        const f32x4 w3 = *(const f32x4*)(srcW + 12);
        char* bA = (char*)&sA[0][0];
        char* bW = (char*)&sW[0][0];
        *(f32x4*)(bA + wb0) = a0; *(f32x4*)(bA + wb1) = a1;
        *(f32x4*)(bA + wb2) = a2; *(f32x4*)(bA + wb3) = a3;
        *(f32x4*)(bW + wb0) = w0; *(f32x4*)(bW + wb1) = w1;
        *(f32x4*)(bW + wb2) = w2; *(f32x4*)(bW + wb3) = w3;
    }
    __syncthreads();

    for (int t = 0; t < NT; ++t) {
        const int  bi   = t & 1;
        const bool more = (t + 1 < NT);
        f32x4 a0, a1, a2, a3, w0, w1, w2, w3;
        if (more) {                    // issue next-tile loads before compute
            const float* pA = srcA + (t + 1) * KT;
            const float* pW = srcW + (t + 1) * KT;
            a0 = *(const f32x4*)(pA);     a1 = *(const f32x4*)(pA + 4);
            a2 = *(const f32x4*)(pA + 8); a3 = *(const f32x4*)(pA + 12);
            w0 = *(const f32x4*)(pW);     w1 = *(const f32x4*)(pW + 4);
            w2 = *(const f32x4*)(pW + 8); w3 = *(const f32x4*)(pW + 12);
        }

        const float* bufA = &sA[bi][0];
        const float* bufW = &sW[bi][0];
        #pragma unroll
        for (int k32 = 0; k32 < 64; k32 += 32) {
            u32x4 ah0, al0, ah1, al1, bh0, bl0, bh1, bl1;
            frag_cvt(bufA, mt0 * 16 + fr,      k32 + fk, ah0, al0);
            frag_cvt(bufA, mt0 * 16 + 16 + fr, k32 + fk, ah1, al1);
            frag_cvt(bufW, nt0 * 16 + fr,      k32 + fk, bh0, bl0);
            frag_cvt(bufW, nt0 * 16 + 16 + fr, k32 + fk, bh1, bl1);
            mfma16(acc00, ah0, bh0); mfma16(acc00, ah0, bl0); mfma16(acc00, al0, bh0);
            mfma16(acc01, ah0, bh1); mfma16(acc01, ah0, bl1); mfma16(acc01, al0, bh1);
            mfma16(acc10, ah1, bh0); mfma16(acc10, ah1, bl0); mfma16(acc10, al1, bh0);
            mfma16(acc11, ah1, bh1); mfma16(acc11, ah1, bl1); mfma16(acc11, al1, bh1);
        }

        if (more) {                    // write prefetched tile into other buf
            char* bA = (char*)&sA[bi ^ 1][0];
            char* bW = (char*)&sW[bi ^ 1][0];
            *(f32x4*)(bA + wb0) = a0; *(f32x4*)(bA + wb1) = a1;
            *(f32x4*)(bA + wb2) = a2; *(f32x4*)(bA + wb3) = a3;
            *(f32x4*)(bW + wb0) = w0; *(f32x4*)(bW + wb1) = w1;
            *(f32x4*)(bW + wb2) = w2; *(f32x4*)(bW + wb3) = w3;
        }
        __syncthreads();
    }

    // ---- store partials: D[row=4*(lane>>4)+r][col=lane&15] per 16x16 tile ----
    float* Pq = P + (size_t)q * NLEAF * EMB;
    const int r0 = (lane >> 4) * 4;
    const int cn = lane & 15;
    #pragma unroll
    for (int r = 0; r < 4; ++r) {
        Pq[(size_t)(gl0 + (mt0 + 0) * 16 + r0 + r) * EMB + (nt0 + 0) * 16 + cn] = acc00[r];
        Pq[(size_t)(gl0 + (mt0 + 0) * 16 + r0 + r) * EMB + (nt0 + 1) * 16 + cn] = acc01[r];
        Pq[(size_t)(gl0 + (mt0 + 1) * 16 + r0 + r) * EMB + (nt0 + 0) * 16 + cn] = acc10[r];
        Pq[(size_t)(gl0 + (mt0 + 1) * 16 + r0 + r) * EMB + (nt0 + 1) * 16 + cn] = acc11[r];
    }
}

// ============================================================================
// Tree helpers (fp32 exact). Lane = output dim e; activations broadcast.
// ============================================================================
__device__ __forceinline__ void load_Wt(float (*Wt)[132],
                                        const float* __restrict__ WW, int tid) {
    const int e  = tid >> 2;
    const int c0 = (tid & 3) * 32;
    #pragma unroll
    for (int j = 0; j < 32; j += 4)
        *(f32x4*)&Wt[e][c0 + j] = *(const f32x4*)&WW[e * 128 + c0 + j];
}

__device__ __forceinline__ float* tree_levels(float* bufA, float* bufB,
        const float (*Wt)[132], float wb, int n0, int nlv, int tid)
{
    const int lane = tid & 63;
    const int wid  = tid >> 6;
    float* src = bufA;
    float* dst = bufB;
    int n = n0;
    for (int lvl = 0; lvl < nlv; ++lvl) {
        const int nodes = n >> 1;
        for (int node = wid; node < nodes; node += 4) {
            const float* p0 = src + (2 * node) * 68;
            const float* p1 = p0 + 68;
            float acc = wb;
            #pragma unroll
            for (int j = 0; j < 16; ++j) {
                const f32x4 w4 = *(const f32x4*)&Wt[lane][4 * j];
                const f32x4 x4 = *(const f32x4*)(p0 + 4 * j);
                acc += w4.x * x4.x + w4.y * x4.y + w4.z * x4.z + w4.w * x4.w;
            }
            #pragma unroll
            for (int j = 0; j < 16; ++j) {
                const f32x4 w4 = *(const f32x4*)&Wt[lane][64 + 4 * j];
                const f32x4 x4 = *(const f32x4*)(p1 + 4 * j);
                acc += w4.x * x4.x + w4.y * x4.y + w4.z * x4.z + w4.w * x4.w;
            }
            dst[node * 68 + lane] = fmaxf(acc, 0.0f);
        }
        __syncthreads();
        float* tswp = src; src = dst; dst = tswp;
        n = nodes;
    }
    return src;   // root row after final swap
}

// K2: combine 4 K-quarter partials + bias + relu, then tree levels 1..5
// (32 leaves -> 1 root per block). grid 256.
__global__ __launch_bounds__(256) void k_tree32(const float* __restrict__ P,
        const float* __restrict__ eb, const float* __restrict__ WW,
        const float* __restrict__ Wb, float* __restrict__ roots)
{
    __shared__ float hA[32][68];
    __shared__ float hB[16][68];
    __shared__ float Wt[64][132];
    const int tid = threadIdx.x;
    const int b   = blockIdx.x;
    load_Wt(Wt, WW, tid);
    {
        const int lf = tid >> 3;
        const int e0 = (tid & 7) * 8;
        const size_t base = (size_t)(b * 32 + lf) * EMB + e0;
        f32x4 s0 = *(const f32x4*)&P[base];
        f32x4 s1 = *(const f32x4*)&P[base + 4];
        s0 += *(const f32x4*)&P[(size_t)1 * NLEAF * EMB + base];
        s1 += *(const f32x4*)&P[(size_t)1 * NLEAF * EMB + base + 4];
        s0 += *(const f32x4*)&P[(size_t)2 * NLEAF * EMB + base];
        s1 += *(const f32x4*)&P[(size_t)2 * NLEAF * EMB + base + 4];
        s0 += *(const f32x4*)&P[(size_t)3 * NLEAF * EMB + base];
        s1 += *(const f32x4*)&P[(size_t)3 * NLEAF * EMB + base + 4];
        s0 += *(const f32x4*)&eb[e0];
        s1 += *(const f32x4*)&eb[e0 + 4];
        s0.x = fmaxf(s0.x, 0.f); s0.y = fmaxf(s0.y, 0.f);
        s0.z = fmaxf(s0.z, 0.f); s0.w = fmaxf(s0.w, 0.f);
        s1.x = fmaxf(s1.x, 0.f); s1.y = fmaxf(s1.y, 0.f);
        s1.z = fmaxf(s1.z, 0.f); s1.w = fmaxf(s1.w, 0.f);
        *(f32x4*)&hA[lf][e0]     = s0;
        *(f32x4*)&hA[lf][e0 + 4] = s1;
    }
    const float wb = Wb[tid & 63];
    __syncthreads();
    float* root = tree_levels(&hA[0][0], &hB[0][0], Wt, wb, 32, 5, tid);
    if (tid < 64) roots[b * 64 + tid] = root[tid];
}

// K3a: 16 roots -> 1 (levels 6..9). grid 16.
__global__ __launch_bounds__(256) void k_tree16(const float* __restrict__ in,
        const float* __restrict__ WW, const float* __restrict__ Wb,
        float* __restrict__ outv)
{
    __shared__ float hA[32][68];
    __shared__ float hB[16][68];
    __shared__ float Wt[64][132];
    const int tid = threadIdx.x;
    load_Wt(Wt, WW, tid);
    {
        const int r  = tid >> 4;
        const int e0 = (tid & 15) * 4;
        *(f32x4*)&hA[r][e0] =
            *(const f32x4*)&in[(size_t)(blockIdx.x * 16 + r) * EMB + e0];
    }
    const float wb = Wb[tid & 63];
    __syncthreads();
    float* root = tree_levels(&hA[0][0], &hB[0][0], Wt, wb, 16, 4, tid);
    if (tid < 64) outv[blockIdx.x * 64 + tid] = root[tid];
}

// K3b: 16 -> 1 (levels 10..13) + projection. grid 1.
__global__ __launch_bounds__(256) void k_root(const float* __restrict__ in,
        const float* __restrict__ WW, const float* __restrict__ Wb,
        const float* __restrict__ pW, const float* __restrict__ pb,
        float* __restrict__ out)
{
    __shared__ float hA[32][68];
    __shared__ float hB[16][68];
    __shared__ float Wt[64][132];
    const int tid = threadIdx.x;
    load_Wt(Wt, WW, tid);
    {
        const int r  = tid >> 4;
        const int e0 = (tid & 15) * 4;
        *(f32x4*)&hA[r][e0] = *(const f32x4*)&in[(size_t)r * EMB + e0];
    }
    const float wb = Wb[tid & 63];
    __syncthreads();
    float* root = tree_levels(&hA[0][0], &hB[0][0], Wt, wb, 16, 4, tid);
    if (tid < 64) {
        const float hv = root[tid];
        float t0 = hv * pW[tid];
        float t1 = hv * pW[64 + tid];
        #pragma unroll
        for (int off = 32; off > 0; off >>= 1) {
            t0 += __shfl_down(t0, off);
            t1 += __shfl_down(t1, off);
        }
        if (tid == 0) { out[0] = t0 + pb[0]; out[1] = t1 + pb[1]; }
    }
}

extern "C" void kernel_launch(void* const* d_in, const int* in_sizes, int n_in,
                              void* d_out, int out_size, void* d_ws, size_t ws_size,
                              hipStream_t stream)
{
    const float* A  = (const float*)d_in[0];   // leaf_seqs [8192][8192]
    const float* eW = (const float*)d_in[1];   // emb_W     [64][8192]
    const float* eb = (const float*)d_in[2];   // emb_b     [64]
    const float* WW = (const float*)d_in[3];   // W_W       [64][128]
    const float* Wb = (const float*)d_in[4];   // W_b       [64]
    const float* pW = (const float*)d_in[5];   // proj_W    [2][64]
    const float* pb = (const float*)d_in[6];   // proj_b    [2]
    float* out = (float*)d_out;

    float* P     = (float*)d_ws;                       // [4][8192][64] f32
    float* roots = P + (size_t)4 * NLEAF * EMB;        // [256][64]
    float* l9    = roots + 256 * EMB;                  // [16][64]

    k_gemm  <<<dim3(512), dim3(256), 0, stream>>>(A, eW, P);
    k_tree32<<<dim3(256), dim3(256), 0, stream>>>(P, eb, WW, Wb, roots);
    k_tree16<<<dim3(16),  dim3(256), 0, stream>>>(roots, WW, Wb, l9);
    k_root  <<<dim3(1),   dim3(256), 0, stream>>>(l9, WW, Wb, pW, pb, out);
}

// Round 2
// 123.521 us; speedup vs baseline: 1.0438x; 1.0438x over previous
//
#include <hip/hip_runtime.h>

#define SEQ   8192
#define EMB   64
#define NLEAF 8192
#define KQ    2048          // K per gemm block (quarter of SEQ)
#define KT    64            // K per LDS tile
#define NT    (KQ / KT)     // 32 tiles

typedef __attribute__((ext_vector_type(4))) float        f32x4;
typedef __attribute__((ext_vector_type(4))) unsigned int u32x4;

// ---- bf16 split helpers (truncation; residual ~2^-16 relative) ----
__device__ __forceinline__ unsigned pack2(float x, float y) {
    return (__float_as_uint(x) >> 16) | (__float_as_uint(y) & 0xffff0000u);
}
__device__ __forceinline__ float bftrunc(float x) {
    return __uint_as_float(__float_as_uint(x) & 0xffff0000u);
}

__device__ __forceinline__ void mfma16(f32x4& d, const u32x4 a, const u32x4 b) {
    asm("v_mfma_f32_16x16x32_bf16 %0, %1, %2, %0" : "+v"(d) : "v"(a), "v"(b));
}

// Read 8 consecutive-k f32 from a swizzled 64x64 f32 LDS tile (256B rows,
// 16B chunk index XORed with row&7), emit hi/lo bf16 fragments (packed pairs).
__device__ __forceinline__ void frag_cvt(const float* buf, int row, int kk,
                                         u32x4& hi, u32x4& lo) {
    const int c = kk >> 2;          // even chunk index
    const int s = row & 7;
    const char* base = (const char*)buf + row * 256;
    const f32x4 v0 = *(const f32x4*)(base + 16 * (c ^ s));
    const f32x4 v1 = *(const f32x4*)(base + 16 * ((c + 1) ^ s));
    u32x4 h, l;
    h[0] = pack2(v0.x, v0.y);
    h[1] = pack2(v0.z, v0.w);
    h[2] = pack2(v1.x, v1.y);
    h[3] = pack2(v1.z, v1.w);
    l[0] = pack2(v0.x - bftrunc(v0.x), v0.y - bftrunc(v0.y));
    l[1] = pack2(v0.z - bftrunc(v0.z), v0.w - bftrunc(v0.w));
    l[2] = pack2(v1.x - bftrunc(v1.x), v1.y - bftrunc(v1.y));
    l[3] = pack2(v1.z - bftrunc(v1.z), v1.w - bftrunc(v1.w));
    hi = h; lo = l;
}

// raw barrier: drain LDS ops for cross-wave visibility, but leave global
// loads in flight (no vmcnt drain -- the m97 barrier-stall killer).
#define SYNC() do { \
    asm volatile("s_waitcnt lgkmcnt(0)" ::: "memory"); \
    __builtin_amdgcn_s_barrier(); \
} while (0)

// ============================================================================
// K1: leaf embedding GEMM, split-bf16 MFMA, K-quarter partials (no bias/relu).
// grid 512 = 128 leaf-groups x 4 k-quarters; block 256; LDS 64KB; 2 blocks/CU.
// Depth-2 register pipeline: loads for tile t+2 issued at iter t.
// ============================================================================
__global__ __launch_bounds__(256, 2) void k_gemm(
        const float* __restrict__ A, const float* __restrict__ W,
        float* __restrict__ P)
{
    __shared__ float sA[2][64 * 64];
    __shared__ float sW[2][64 * 64];

    const int tid  = threadIdx.x;
    const int lane = tid & 63;
    const int wid  = tid >> 6;

    const int g     = blockIdx.x >> 2;   // leaf group (64 leaves)
    const int q     = blockIdx.x & 3;    // k quarter
    const int gl0   = g * 64;
    const int kbase = q * KQ;

    // ---- staging map: thread -> (row sr, 64B col-chunk sq) of both tiles ----
    const int sr = tid & 63;
    const int sq = tid >> 6;
    const float* srcA = A + (size_t)(gl0 + sr) * SEQ + kbase + sq * 16;
    const float* srcW = W + (size_t)sr * SEQ + kbase + sq * 16;
    const int wb0 = sr * 256 + 16 * (((sq * 4) + 0) ^ (sr & 7));
    const int wb1 = sr * 256 + 16 * (((sq * 4) + 1) ^ (sr & 7));
    const int wb2 = sr * 256 + 16 * (((sq * 4) + 2) ^ (sr & 7));
    const int wb3 = sr * 256 + 16 * (((sq * 4) + 3) ^ (sr & 7));

    // ---- per-wave output tiles: wave -> (m-pair, n-pair) of 16x16 tiles ----
    const int mt0 = (wid & 1) * 2;
    const int nt0 = (wid >> 1) * 2;
    const int fr  = lane & 15;
    const int fk  = (lane >> 4) * 8;

    f32x4 acc00 = {0.f, 0.f, 0.f, 0.f};
    f32x4 acc01 = {0.f, 0.f, 0.f, 0.f};
    f32x4 acc10 = {0.f, 0.f, 0.f, 0.f};
    f32x4 acc11 = {0.f, 0.f, 0.f, 0.f};

    f32x4 rA0[4], rW0[4], rA1[4], rW1[4];

#define LOADSET(rA_, rW_, tt) do { \
    const float* pA_ = srcA + (tt) * KT; \
    const float* pW_ = srcW + (tt) * KT; \
    rA_[0] = *(const f32x4*)(pA_);      rA_[1] = *(const f32x4*)(pA_ + 4); \
    rA_[2] = *(const f32x4*)(pA_ + 8);  rA_[3] = *(const f32x4*)(pA_ + 12); \
    rW_[0] = *(const f32x4*)(pW_);      rW_[1] = *(const f32x4*)(pW_ + 4); \
    rW_[2] = *(const f32x4*)(pW_ + 8);  rW_[3] = *(const f32x4*)(pW_ + 12); \
} while (0)

#define WRITESET(rA_, rW_, bi_) do { \
    char* bA_ = (char*)&sA[bi_][0]; \
    char* bW_ = (char*)&sW[bi_][0]; \
    *(f32x4*)(bA_ + wb0) = rA_[0]; *(f32x4*)(bA_ + wb1) = rA_[1]; \
    *(f32x4*)(bA_ + wb2) = rA_[2]; *(f32x4*)(bA_ + wb3) = rA_[3]; \
    *(f32x4*)(bW_ + wb0) = rW_[0]; *(f32x4*)(bW_ + wb1) = rW_[1]; \
    *(f32x4*)(bW_ + wb2) = rW_[2]; *(f32x4*)(bW_ + wb3) = rW_[3]; \
} while (0)

#define COMPUTE(bi_) do { \
    const float* bufA_ = &sA[bi_][0]; \
    const float* bufW_ = &sW[bi_][0]; \
    _Pragma("unroll") \
    for (int k32 = 0; k32 < 64; k32 += 32) { \
        u32x4 ah0, al0, ah1, al1, bh0, bl0, bh1, bl1; \
        frag_cvt(bufA_, mt0 * 16 + fr,      k32 + fk, ah0, al0); \
        frag_cvt(bufA_, mt0 * 16 + 16 + fr, k32 + fk, ah1, al1); \
        frag_cvt(bufW_, nt0 * 16 + fr,      k32 + fk, bh0, bl0); \
        frag_cvt(bufW_, nt0 * 16 + 16 + fr, k32 + fk, bh1, bl1); \
        mfma16(acc00, ah0, bh0); mfma16(acc00, ah0, bl0); mfma16(acc00, al0, bh0); \
        mfma16(acc01, ah0, bh1); mfma16(acc01, ah0, bl1); mfma16(acc01, al0, bh1); \
        mfma16(acc10, ah1, bh0); mfma16(acc10, ah1, bl0); mfma16(acc10, al1, bh0); \
        mfma16(acc11, ah1, bh1); mfma16(acc11, ah1, bl1); mfma16(acc11, al1, bh1); \
    } \
} while (0)

    // prologue: tiles 0 and 1 into register sets; tile 0 into LDS buf0
    LOADSET(rA0, rW0, 0);
    LOADSET(rA1, rW1, 1);
    WRITESET(rA0, rW0, 0);
    SYNC();

    #pragma unroll 1
    for (int i = 0; i < NT / 2; ++i) {
        const int t = 2 * i;
        // phase A: tile t in buf0
        if (t + 2 < NT) LOADSET(rA0, rW0, t + 2);
        COMPUTE(0);
        WRITESET(rA1, rW1, 1);               // tile t+1 -> buf1 (t+1 < NT always)
        SYNC();
        // phase B: tile t+1 in buf1
        if (t + 3 < NT) LOADSET(rA1, rW1, t + 3);
        COMPUTE(1);
        if (t + 2 < NT) WRITESET(rA0, rW0, 0);
        SYNC();
    }

#undef LOADSET
#undef WRITESET
#undef COMPUTE

    // ---- store partials: D[row=4*(lane>>4)+r][col=lane&15] per 16x16 tile ----
    float* Pq = P + (size_t)q * NLEAF * EMB;
    const int r0 = (lane >> 4) * 4;
    const int cn = lane & 15;
    #pragma unroll
    for (int r = 0; r < 4; ++r) {
        Pq[(size_t)(gl0 + (mt0 + 0) * 16 + r0 + r) * EMB + (nt0 + 0) * 16 + cn] = acc00[r];
        Pq[(size_t)(gl0 + (mt0 + 0) * 16 + r0 + r) * EMB + (nt0 + 1) * 16 + cn] = acc01[r];
        Pq[(size_t)(gl0 + (mt0 + 1) * 16 + r0 + r) * EMB + (nt0 + 0) * 16 + cn] = acc10[r];
        Pq[(size_t)(gl0 + (mt0 + 1) * 16 + r0 + r) * EMB + (nt0 + 1) * 16 + cn] = acc11[r];
    }
}

// ============================================================================
// Tree helpers (fp32). Lane = output dim e; activations broadcast.
// Vector accumulators: 8 parallel FMA chains instead of 1 scalar chain.
// ============================================================================
__device__ __forceinline__ void load_Wt(float (*Wt)[132],
                                        const float* __restrict__ WW, int tid) {
    const int e  = tid >> 2;
    const int c0 = (tid & 3) * 32;
    #pragma unroll
    for (int j = 0; j < 32; j += 4)
        *(f32x4*)&Wt[e][c0 + j] = *(const f32x4*)&WW[e * 128 + c0 + j];
}

__device__ __forceinline__ float* tree_levels(float* bufA, float* bufB,
        const float (*Wt)[132], float wb, int n0, int nlv, int tid)
{
    const int lane = tid & 63;
    const int wid  = tid >> 6;
    float* src = bufA;
    float* dst = bufB;
    int n = n0;
    for (int lvl = 0; lvl < nlv; ++lvl) {
        const int nodes = n >> 1;
        for (int node = wid; node < nodes; node += 4) {
            const float* p0 = src + (2 * node) * 68;
            const float* p1 = p0 + 68;
            f32x4 a0 = {0.f, 0.f, 0.f, 0.f};
            f32x4 a1 = {0.f, 0.f, 0.f, 0.f};
            #pragma unroll
            for (int j = 0; j < 16; ++j) {
                a0 += *(const f32x4*)&Wt[lane][4 * j]      * *(const f32x4*)(p0 + 4 * j);
                a1 += *(const f32x4*)&Wt[lane][64 + 4 * j] * *(const f32x4*)(p1 + 4 * j);
            }
            const f32x4 a = a0 + a1;
            dst[node * 68 + lane] = fmaxf(wb + a.x + a.y + a.z + a.w, 0.0f);
        }
        __syncthreads();
        float* tswp = src; src = dst; dst = tswp;
        n = nodes;
    }
    return src;   // root row after final swap
}

// K2: combine 4 K-quarter partials + bias + relu, then tree levels 1..5
// (32 leaves -> 1 root per block). grid 256.
__global__ __launch_bounds__(256) void k_tree32(const float* __restrict__ P,
        const float* __restrict__ eb, const float* __restrict__ WW,
        const float* __restrict__ Wb, float* __restrict__ roots)
{
    __shared__ float hA[32][68];
    __shared__ float hB[16][68];
    __shared__ float Wt[64][132];
    const int tid = threadIdx.x;
    const int b   = blockIdx.x;
    load_Wt(Wt, WW, tid);
    {
        const int lf = tid >> 3;
        const int e0 = (tid & 7) * 8;
        const size_t base = (size_t)(b * 32 + lf) * EMB + e0;
        f32x4 s0 = *(const f32x4*)&P[base];
        f32x4 s1 = *(const f32x4*)&P[base + 4];
        s0 += *(const f32x4*)&P[(size_t)1 * NLEAF * EMB + base];
        s1 += *(const f32x4*)&P[(size_t)1 * NLEAF * EMB + base + 4];
        s0 += *(const f32x4*)&P[(size_t)2 * NLEAF * EMB + base];
        s1 += *(const f32x4*)&P[(size_t)2 * NLEAF * EMB + base + 4];
        s0 += *(const f32x4*)&P[(size_t)3 * NLEAF * EMB + base];
        s1 += *(const f32x4*)&P[(size_t)3 * NLEAF * EMB + base + 4];
        s0 += *(const f32x4*)&eb[e0];
        s1 += *(const f32x4*)&eb[e0 + 4];
        s0.x = fmaxf(s0.x, 0.f); s0.y = fmaxf(s0.y, 0.f);
        s0.z = fmaxf(s0.z, 0.f); s0.w = fmaxf(s0.w, 0.f);
        s1.x = fmaxf(s1.x, 0.f); s1.y = fmaxf(s1.y, 0.f);
        s1.z = fmaxf(s1.z, 0.f); s1.w = fmaxf(s1.w, 0.f);
        *(f32x4*)&hA[lf][e0]     = s0;
        *(f32x4*)&hA[lf][e0 + 4] = s1;
    }
    const float wb = Wb[tid & 63];
    __syncthreads();
    float* root = tree_levels(&hA[0][0], &hB[0][0], Wt, wb, 32, 5, tid);
    if (tid < 64) roots[b * 64 + tid] = root[tid];
}

// K3a: 16 roots -> 1 (levels 6..9). grid 16.
__global__ __launch_bounds__(256) void k_tree16(const float* __restrict__ in,
        const float* __restrict__ WW, const float* __restrict__ Wb,
        float* __restrict__ outv)
{
    __shared__ float hA[32][68];
    __shared__ float hB[16][68];
    __shared__ float Wt[64][132];
    const int tid = threadIdx.x;
    load_Wt(Wt, WW, tid);
    {
        const int r  = tid >> 4;
        const int e0 = (tid & 15) * 4;
        *(f32x4*)&hA[r][e0] =
            *(const f32x4*)&in[(size_t)(blockIdx.x * 16 + r) * EMB + e0];
    }
    const float wb = Wb[tid & 63];
    __syncthreads();
    float* root = tree_levels(&hA[0][0], &hB[0][0], Wt, wb, 16, 4, tid);
    if (tid < 64) outv[blockIdx.x * 64 + tid] = root[tid];
}

// K3b: 16 -> 1 (levels 10..13) + projection. grid 1.
__global__ __launch_bounds__(256) void k_root(const float* __restrict__ in,
        const float* __restrict__ WW, const float* __restrict__ Wb,
        const float* __restrict__ pW, const float* __restrict__ pb,
        float* __restrict__ out)
{
    __shared__ float hA[32][68];
    __shared__ float hB[16][68];
    __shared__ float Wt[64][132];
    const int tid = threadIdx.x;
    load_Wt(Wt, WW, tid);
    {
        const int r  = tid >> 4;
        const int e0 = (tid & 15) * 4;
        *(f32x4*)&hA[r][e0] = *(const f32x4*)&in[(size_t)r * EMB + e0];
    }
    const float wb = Wb[tid & 63];
    __syncthreads();
    float* root = tree_levels(&hA[0][0], &hB[0][0], Wt, wb, 16, 4, tid);
    if (tid < 64) {
        const float hv = root[tid];
        float t0 = hv * pW[tid];
        float t1 = hv * pW[64 + tid];
        #pragma unroll
        for (int off = 32; off > 0; off >>= 1) {
            t0 += __shfl_down(t0, off);
            t1 += __shfl_down(t1, off);
        }
        if (tid == 0) { out[0] = t0 + pb[0]; out[1] = t1 + pb[1]; }
    }
}

extern "C" void kernel_launch(void* const* d_in, const int* in_sizes, int n_in,
                              void* d_out, int out_size, void* d_ws, size_t ws_size,
                              hipStream_t stream)
{
    const float* A  = (const float*)d_in[0];   // leaf_seqs [8192][8192]
    const float* eW = (const float*)d_in[1];   // emb_W     [64][8192]
    const float* eb = (const float*)d_in[2];   // emb_b     [64]
    const float* WW = (const float*)d_in[3];   // W_W       [64][128]
    const float* Wb = (const float*)d_in[4];   // W_b       [64]
    const float* pW = (const float*)d_in[5];   // proj_W    [2][64]
    const float* pb = (const float*)d_in[6];   // proj_b    [2]
    float* out = (float*)d_out;

    float* P     = (float*)d_ws;                       // [4][8192][64] f32
    float* roots = P + (size_t)4 * NLEAF * EMB;        // [256][64]
    float* l9    = roots + 256 * EMB;                  // [16][64]

    k_gemm  <<<dim3(512), dim3(256), 0, stream>>>(A, eW, P);
    k_tree32<<<dim3(256), dim3(256), 0, stream>>>(P, eb, WW, Wb, roots);
    k_tree16<<<dim3(16),  dim3(256), 0, stream>>>(roots, WW, Wb, l9);
    k_root  <<<dim3(1),   dim3(256), 0, stream>>>(l9, WW, Wb, pW, pb, out);
}

// Round 3
// 91.559 us; speedup vs baseline: 1.4081x; 1.3491x over previous
//
#include <hip/hip_runtime.h>

#define SEQ   8192
#define EMB   64
#define NLEAF 8192
#define KQ    2048          // K per gemm block (quarter of SEQ)
#define KT    64            // K per LDS tile
#define NT    (KQ / KT)     // 32 tiles

typedef __attribute__((ext_vector_type(4))) float        f32x4;
typedef __attribute__((ext_vector_type(4))) unsigned int u32x4;

// ---- bf16 split helpers (truncation; residual ~2^-16 relative) ----
__device__ __forceinline__ unsigned pack2(float x, float y) {
    // bytes [x2,x3,y2,y3] == (bits(x)>>16) | (bits(y)&0xffff0000) -- 1 v_perm_b32
    return __builtin_amdgcn_perm(__float_as_uint(y), __float_as_uint(x), 0x07060302u);
}
__device__ __forceinline__ float bftrunc(float x) {
    return __uint_as_float(__float_as_uint(x) & 0xffff0000u);
}

__device__ __forceinline__ void mfma16(f32x4& d, const u32x4 a, const u32x4 b) {
    asm("v_mfma_f32_16x16x32_bf16 %0, %1, %2, %0" : "+v"(d) : "v"(a), "v"(b));
}

// Read 8 consecutive-k f32 from a swizzled 64x64 f32 LDS tile (256B rows,
// 16B chunk index XORed with row&7), emit hi/lo bf16 fragments (packed pairs).
__device__ __forceinline__ void frag_cvt(const float* buf, int row, int kk,
                                         u32x4& hi, u32x4& lo) {
    const int c = kk >> 2;          // even chunk index
    const int s = row & 7;
    const char* base = (const char*)buf + row * 256;
    const f32x4 v0 = *(const f32x4*)(base + 16 * (c ^ s));
    const f32x4 v1 = *(const f32x4*)(base + 16 * ((c + 1) ^ s));
    u32x4 h, l;
    h[0] = pack2(v0.x, v0.y);
    h[1] = pack2(v0.z, v0.w);
    h[2] = pack2(v1.x, v1.y);
    h[3] = pack2(v1.z, v1.w);
    l[0] = pack2(v0.x - bftrunc(v0.x), v0.y - bftrunc(v0.y));
    l[1] = pack2(v0.z - bftrunc(v0.z), v0.w - bftrunc(v0.w));
    l[2] = pack2(v1.x - bftrunc(v1.x), v1.y - bftrunc(v1.y));
    l[3] = pack2(v1.z - bftrunc(v1.z), v1.w - bftrunc(v1.w));
    hi = h; lo = l;
}

// async global->LDS, 16B per lane; lptr must be wave-uniform (HW adds lane*16)
#define GLDS16(gp, lp) \
    __builtin_amdgcn_global_load_lds( \
        (const __attribute__((address_space(1))) void*)(gp), \
        (__attribute__((address_space(3))) void*)(lp), 16, 0, 0)

// ============================================================================
// K1: leaf embedding GEMM, split-bf16 MFMA, K-quarter partials (no bias/relu).
// grid 512 = 128 leaf-groups x 4 k-quarters; block 256; LDS 64KB; 2 blocks/CU.
// Staging: global_load_lds dwordx4; wave w inst j covers 4 rows x 256B
// contiguous (16 lanes sequential per row). Read-side XOR swizzle achieved by
// pre-swizzling the global source chunk (rule #21: linear dest + inv-swz src).
// ============================================================================
__global__ __launch_bounds__(256, 2) void k_gemm(
        const float* __restrict__ A, const float* __restrict__ W,
        float* __restrict__ P)
{
    __shared__ float sA[2][64 * 64];
    __shared__ float sW[2][64 * 64];

    const int tid  = threadIdx.x;
    const int lane = tid & 63;
    const int wid  = tid >> 6;

    const int g     = blockIdx.x >> 2;   // leaf group (64 leaves)
    const int q     = blockIdx.x & 3;    // k quarter
    const int gl0   = g * 64;
    const int kbase = q * KQ;

    const int lr = lane >> 4;            // row within 4-row group
    const int lc = lane & 15;            // LDS 16B-chunk within row

    // per-j (4-row group) global source pointers, chunk pre-swizzled
    const float* pA[4];
    const float* pW[4];
    #pragma unroll
    for (int j = 0; j < 4; ++j) {
        const int row = wid * 16 + j * 4 + lr;       // row within 64-row tile
        const int ch  = lc ^ ((j * 4 + lr) & 7);     // inv-swizzled chunk
        pA[j] = A + (size_t)(gl0 + row) * SEQ + kbase + ch * 4;
        pW[j] = W + (size_t)row * SEQ + kbase + ch * 4;
    }

    // ---- per-wave output tiles: wave -> (m-pair, n-pair) of 16x16 tiles ----
    const int mt0 = (wid & 1) * 2;
    const int nt0 = (wid >> 1) * 2;
    const int fr  = lane & 15;
    const int fk  = (lane >> 4) * 8;

    f32x4 acc00 = {0.f, 0.f, 0.f, 0.f};
    f32x4 acc01 = {0.f, 0.f, 0.f, 0.f};
    f32x4 acc10 = {0.f, 0.f, 0.f, 0.f};
    f32x4 acc11 = {0.f, 0.f, 0.f, 0.f};

#define STAGE(bi_) do { \
    _Pragma("unroll") \
    for (int j = 0; j < 4; ++j) { \
        GLDS16(pA[j], &sA[bi_][(wid * 16 + j * 4) * 64]); \
        GLDS16(pW[j], &sW[bi_][(wid * 16 + j * 4) * 64]); \
        pA[j] += KT; pW[j] += KT; \
    } \
} while (0)

#define COMPUTE(bi_) do { \
    const float* bufA_ = &sA[bi_][0]; \
    const float* bufW_ = &sW[bi_][0]; \
    _Pragma("unroll") \
    for (int k32 = 0; k32 < 64; k32 += 32) { \
        u32x4 ah0, al0, ah1, al1, bh0, bl0, bh1, bl1; \
        frag_cvt(bufA_, mt0 * 16 + fr,      k32 + fk, ah0, al0); \
        frag_cvt(bufA_, mt0 * 16 + 16 + fr, k32 + fk, ah1, al1); \
        frag_cvt(bufW_, nt0 * 16 + fr,      k32 + fk, bh0, bl0); \
        frag_cvt(bufW_, nt0 * 16 + 16 + fr, k32 + fk, bh1, bl1); \
        mfma16(acc00, ah0, bh0); mfma16(acc00, ah0, bl0); mfma16(acc00, al0, bh0); \
        mfma16(acc01, ah0, bh1); mfma16(acc01, ah0, bl1); mfma16(acc01, al0, bh1); \
        mfma16(acc10, ah1, bh0); mfma16(acc10, ah1, bl0); mfma16(acc10, al1, bh0); \
        mfma16(acc11, ah1, bh1); mfma16(acc11, ah1, bl1); mfma16(acc11, al1, bh1); \
    } \
} while (0)

    // prologue: stage tile 0 into buf0 and wait for it
    STAGE(0);
    asm volatile("s_waitcnt vmcnt(0)" ::: "memory");
    __builtin_amdgcn_s_barrier();
    asm volatile("" ::: "memory");

    #pragma unroll 1
    for (int t = 0; t < NT; ++t) {
        const int p = t & 1;
        if (t + 1 < NT) {
            STAGE(p ^ 1);                          // issue next tile early
            asm volatile("" ::: "memory");         // pin issue order
        }
        COMPUTE(p);
        asm volatile("s_waitcnt vmcnt(0) lgkmcnt(0)" ::: "memory");
        __builtin_amdgcn_s_barrier();
        asm volatile("" ::: "memory");
    }

#undef STAGE
#undef COMPUTE

    // ---- store partials: D[row=4*(lane>>4)+r][col=lane&15] per 16x16 tile ----
    float* Pq = P + (size_t)q * NLEAF * EMB;
    const int r0 = (lane >> 4) * 4;
    const int cn = lane & 15;
    #pragma unroll
    for (int r = 0; r < 4; ++r) {
        Pq[(size_t)(gl0 + (mt0 + 0) * 16 + r0 + r) * EMB + (nt0 + 0) * 16 + cn] = acc00[r];
        Pq[(size_t)(gl0 + (mt0 + 0) * 16 + r0 + r) * EMB + (nt0 + 1) * 16 + cn] = acc01[r];
        Pq[(size_t)(gl0 + (mt0 + 1) * 16 + r0 + r) * EMB + (nt0 + 0) * 16 + cn] = acc10[r];
        Pq[(size_t)(gl0 + (mt0 + 1) * 16 + r0 + r) * EMB + (nt0 + 1) * 16 + cn] = acc11[r];
    }
}

// ============================================================================
// Tree helpers (fp32 exact). Lane = output dim e; activations broadcast.
// 4 nodes per wave per pass: amortizes the Wt[lane][*] (8-way bank) reads x4.
// ============================================================================
__device__ __forceinline__ void load_Wt(float (*Wt)[132],
                                        const float* __restrict__ WW, int tid) {
    const int e  = tid >> 2;
    const int c0 = (tid & 3) * 32;
    #pragma unroll
    for (int j = 0; j < 32; j += 4)
        *(f32x4*)&Wt[e][c0 + j] = *(const f32x4*)&WW[e * 128 + c0 + j];
}

__device__ __forceinline__ float hsum4(const f32x4 a) {
    return a.x + a.y + a.z + a.w;
}

__device__ __forceinline__ float* tree_levels(float* bufA, float* bufB,
        const float (*Wt)[132], float wb, int n0, int nlv, int tid)
{
    const int lane = tid & 63;
    const int wid  = tid >> 6;
    float* src = bufA;
    float* dst = bufB;
    int n = n0;
    for (int lvl = 0; lvl < nlv; ++lvl) {
        const int nodes = n >> 1;
        for (int base = wid * 4; base < nodes; base += 16) {
            const int cnt = (nodes - base < 4) ? (nodes - base) : 4;
            if (cnt == 4) {
                f32x4 ac0 = {0.f,0.f,0.f,0.f}, ac1 = ac0, ac2 = ac0, ac3 = ac0;
                const float* x0 = src + (2 * (base + 0)) * 68;
                const float* x1 = src + (2 * (base + 1)) * 68;
                const float* x2 = src + (2 * (base + 2)) * 68;
                const float* x3 = src + (2 * (base + 3)) * 68;
                #pragma unroll
                for (int j = 0; j < 32; ++j) {
                    const f32x4 w4 = *(const f32x4*)&Wt[lane][4 * j];
                    const int off = (j < 16) ? (4 * j) : (68 + 4 * (j - 16));
                    ac0 += w4 * *(const f32x4*)(x0 + off);
                    ac1 += w4 * *(const f32x4*)(x1 + off);
                    ac2 += w4 * *(const f32x4*)(x2 + off);
                    ac3 += w4 * *(const f32x4*)(x3 + off);
                }
                dst[(base + 0) * 68 + lane] = fmaxf(wb + hsum4(ac0), 0.f);
                dst[(base + 1) * 68 + lane] = fmaxf(wb + hsum4(ac1), 0.f);
                dst[(base + 2) * 68 + lane] = fmaxf(wb + hsum4(ac2), 0.f);
                dst[(base + 3) * 68 + lane] = fmaxf(wb + hsum4(ac3), 0.f);
            } else {
                for (int u = 0; u < cnt; ++u) {
                    f32x4 ac = {0.f, 0.f, 0.f, 0.f};
                    const float* x = src + (2 * (base + u)) * 68;
                    #pragma unroll
                    for (int j = 0; j < 32; ++j) {
                        const f32x4 w4 = *(const f32x4*)&Wt[lane][4 * j];
                        const int off = (j < 16) ? (4 * j) : (68 + 4 * (j - 16));
                        ac += w4 * *(const f32x4*)(x + off);
                    }
                    dst[(base + u) * 68 + lane] = fmaxf(wb + hsum4(ac), 0.f);
                }
            }
        }
        __syncthreads();
        float* tswp = src; src = dst; dst = tswp;
        n = nodes;
    }
    return src;   // root row after final swap
}

// K2: combine 4 K-quarter partials + bias + relu, then tree levels 1..5
// (32 leaves -> 1 root per block). grid 256.
__global__ __launch_bounds__(256) void k_tree32(const float* __restrict__ P,
        const float* __restrict__ eb, const float* __restrict__ WW,
        const float* __restrict__ Wb, float* __restrict__ roots)
{
    __shared__ float hA[32][68];
    __shared__ float hB[16][68];
    __shared__ float Wt[64][132];
    const int tid = threadIdx.x;
    const int b   = blockIdx.x;
    load_Wt(Wt, WW, tid);
    {
        const int lf = tid >> 3;
        const int e0 = (tid & 7) * 8;
        const size_t base = (size_t)(b * 32 + lf) * EMB + e0;
        f32x4 s0 = *(const f32x4*)&P[base];
        f32x4 s1 = *(const f32x4*)&P[base + 4];
        s0 += *(const f32x4*)&P[(size_t)1 * NLEAF * EMB + base];
        s1 += *(const f32x4*)&P[(size_t)1 * NLEAF * EMB + base + 4];
        s0 += *(const f32x4*)&P[(size_t)2 * NLEAF * EMB + base];
        s1 += *(const f32x4*)&P[(size_t)2 * NLEAF * EMB + base + 4];
        s0 += *(const f32x4*)&P[(size_t)3 * NLEAF * EMB + base];
        s1 += *(const f32x4*)&P[(size_t)3 * NLEAF * EMB + base + 4];
        s0 += *(const f32x4*)&eb[e0];
        s1 += *(const f32x4*)&eb[e0 + 4];
        s0.x = fmaxf(s0.x, 0.f); s0.y = fmaxf(s0.y, 0.f);
        s0.z = fmaxf(s0.z, 0.f); s0.w = fmaxf(s0.w, 0.f);
        s1.x = fmaxf(s1.x, 0.f); s1.y = fmaxf(s1.y, 0.f);
        s1.z = fmaxf(s1.z, 0.f); s1.w = fmaxf(s1.w, 0.f);
        *(f32x4*)&hA[lf][e0]     = s0;
        *(f32x4*)&hA[lf][e0 + 4] = s1;
    }
    const float wb = Wb[tid & 63];
    __syncthreads();
    float* root = tree_levels(&hA[0][0], &hB[0][0], Wt, wb, 32, 5, tid);
    if (tid < 64) roots[b * 64 + tid] = root[tid];
}

// K3a: 16 roots -> 1 (levels 6..9). grid 16.
__global__ __launch_bounds__(256) void k_tree16(const float* __restrict__ in,
        const float* __restrict__ WW, const float* __restrict__ Wb,
        float* __restrict__ outv)
{
    __shared__ float hA[32][68];
    __shared__ float hB[16][68];
    __shared__ float Wt[64][132];
    const int tid = threadIdx.x;
    load_Wt(Wt, WW, tid);
    {
        const int r  = tid >> 4;
        const int e0 = (tid & 15) * 4;
        *(f32x4*)&hA[r][e0] =
            *(const f32x4*)&in[(size_t)(blockIdx.x * 16 + r) * EMB + e0];
    }
    const float wb = Wb[tid & 63];
    __syncthreads();
    float* root = tree_levels(&hA[0][0], &hB[0][0], Wt, wb, 16, 4, tid);
    if (tid < 64) outv[blockIdx.x * 64 + tid] = root[tid];
}

// K3b: 16 -> 1 (levels 10..13) + projection. grid 1.
__global__ __launch_bounds__(256) void k_root(const float* __restrict__ in,
        const float* __restrict__ WW, const float* __restrict__ Wb,
        const float* __restrict__ pW, const float* __restrict__ pb,
        float* __restrict__ out)
{
    __shared__ float hA[32][68];
    __shared__ float hB[16][68];
    __shared__ float Wt[64][132];
    const int tid = threadIdx.x;
    load_Wt(Wt, WW, tid);
    {
        const int r  = tid >> 4;
        const int e0 = (tid & 15) * 4;
        *(f32x4*)&hA[r][e0] = *(const f32x4*)&in[(size_t)r * EMB + e0];
    }
    const float wb = Wb[tid & 63];
    __syncthreads();
    float* root = tree_levels(&hA[0][0], &hB[0][0], Wt, wb, 16, 4, tid);
    if (tid < 64) {
        const float hv = root[tid];
        float t0 = hv * pW[tid];
        float t1 = hv * pW[64 + tid];
        #pragma unroll
        for (int off = 32; off > 0; off >>= 1) {
            t0 += __shfl_down(t0, off);
            t1 += __shfl_down(t1, off);
        }
        if (tid == 0) { out[0] = t0 + pb[0]; out[1] = t1 + pb[1]; }
    }
}

extern "C" void kernel_launch(void* const* d_in, const int* in_sizes, int n_in,
                              void* d_out, int out_size, void* d_ws, size_t ws_size,
                              hipStream_t stream)
{
    const float* A  = (const float*)d_in[0];   // leaf_seqs [8192][8192]
    const float* eW = (const float*)d_in[1];   // emb_W     [64][8192]
    const float* eb = (const float*)d_in[2];   // emb_b     [64]
    const float* WW = (const float*)d_in[3];   // W_W       [64][128]
    const float* Wb = (const float*)d_in[4];   // W_b       [64]
    const float* pW = (const float*)d_in[5];   // proj_W    [2][64]
    const float* pb = (const float*)d_in[6];   // proj_b    [2]
    float* out = (float*)d_out;

    float* P     = (float*)d_ws;                       // [4][8192][64] f32
    float* roots = P + (size_t)4 * NLEAF * EMB;        // [256][64]
    float* l9    = roots + 256 * EMB;                  // [16][64]

    k_gemm  <<<dim3(512), dim3(256), 0, stream>>>(A, eW, P);
    k_tree32<<<dim3(256), dim3(256), 0, stream>>>(P, eb, WW, Wb, roots);
    k_tree16<<<dim3(16),  dim3(256), 0, stream>>>(roots, WW, Wb, l9);
    k_root  <<<dim3(1),   dim3(256), 0, stream>>>(l9, WW, Wb, pW, pb, out);
}

// Round 5
// 82.895 us; speedup vs baseline: 1.5553x; 1.1045x over previous
//
#include <hip/hip_runtime.h>

#define SEQ   8192
#define EMB   64
#define NLEAF 8192
#define KQ    2048          // K per gemm block (quarter of SEQ)
#define KT    64            // K per LDS tile
#define NT    (KQ / KT)     // 32 tiles

typedef __attribute__((ext_vector_type(4))) float        f32x4;
typedef __attribute__((ext_vector_type(4))) unsigned int u32x4;

// ---- bf16 RNE pack: pair (x,y) -> [bf16(x) | bf16(y)<<16] ----
__device__ __forceinline__ unsigned rne_pair(float x, float y) {
    const unsigned ux = __float_as_uint(x), uy = __float_as_uint(y);
    const unsigned rx = (ux + 0x7fffu + ((ux >> 16) & 1u)) >> 16;
    const unsigned ry = (uy + 0x7fffu + ((uy >> 16) & 1u)) & 0xffff0000u;
    return rx | ry;
}

__device__ __forceinline__ void mfma16(f32x4& d, const u32x4 a, const u32x4 b) {
    asm("v_mfma_f32_16x16x32_bf16 %0, %1, %2, %0" : "+v"(d) : "v"(a), "v"(b));
}

// Read 8 consecutive-k f32 from a swizzled 64x64 f32 LDS tile (256B rows,
// 16B chunk index XORed with row&7), emit one RNE bf16 fragment.
__device__ __forceinline__ u32x4 frag_rne(const float* buf, int row, int kk) {
    const int c = kk >> 2;          // even chunk index
    const int s = row & 7;
    const char* base = (const char*)buf + row * 256;
    const f32x4 v0 = *(const f32x4*)(base + 16 * (c ^ s));
    const f32x4 v1 = *(const f32x4*)(base + 16 * ((c + 1) ^ s));
    u32x4 h;
    h[0] = rne_pair(v0.x, v0.y);
    h[1] = rne_pair(v0.z, v0.w);
    h[2] = rne_pair(v1.x, v1.y);
    h[3] = rne_pair(v1.z, v1.w);
    return h;
}

// async global->LDS, 16B per lane; offset immediate ALWAYS 0 (nonzero offset
// semantics are ambiguous for LDS-DMA -- R4's failure; bake offsets into the
// pointer instead). LDS dest wave-uniform; HW adds lane*16.
#define GLDS16(gp, lp) \
    __builtin_amdgcn_global_load_lds( \
        (const __attribute__((address_space(1))) void*)(gp), \
        (__attribute__((address_space(3))) void*)(lp), 16, 0, 0)

// ============================================================================
// K0: W [64][8192] f32 -> bf16 RNE, laid out as per-tile LDS images (8KB each,
// row*128 + chsw*16, content chunk = chsw ^ (row&7)) so k_gemm stages with
// purely linear glds. grid 256 x 256.
// ============================================================================
__global__ __launch_bounds__(256) void k_cvtW(const float* __restrict__ W,
                                              unsigned* __restrict__ Wt)
{
    const int gid  = blockIdx.x * 256 + threadIdx.x;   // 65536 = 4*32*64*8
    const int chsw = gid & 7;
    const int row  = (gid >> 3) & 63;
    const int t    = (gid >> 9) & 31;
    const int q    = gid >> 14;
    const int c    = chsw ^ (row & 7);
    const float* src = W + (size_t)row * SEQ + q * KQ + t * KT + c * 8;
    const f32x4 a = *(const f32x4*)(src);
    const f32x4 b = *(const f32x4*)(src + 4);
    u32x4 v;
    v[0] = rne_pair(a.x, a.y);
    v[1] = rne_pair(a.z, a.w);
    v[2] = rne_pair(b.x, b.y);
    v[3] = rne_pair(b.z, b.w);
    // byte addr = (q*32+t)*8192 + row*128 + chsw*16
    u32x4* dst = (u32x4*)(Wt + ((q * 32 + t) * 512 + row * 8 + chsw) * 4);
    *dst = v;
}

// ============================================================================
// K1: leaf embedding GEMM, pure bf16 RNE MFMA, K-quarter partials.
// grid 512 = 128 leaf-groups x 4 k-quarters; block 256 (4 waves); 72KB LDS;
// 2 blocks/CU. Wave w owns leaves [16w,16w+16) x all 64 emb (4 acc tiles).
// 3-buffer depth-2 pipeline, counted vmcnt(6) -- never drains in the loop.
// ============================================================================
__global__ __launch_bounds__(256, 2) void k_gemm(
        const float* __restrict__ A, const char* __restrict__ Wt,
        float* __restrict__ P)
{
    __shared__ float sA[3][64 * 64];        // f32 A tiles, swizzled rows
    __shared__ char  sW[3][8192];           // bf16 W tile images

    const int tid  = threadIdx.x;
    const int lane = tid & 63;
    const int wid  = tid >> 6;

    const int g     = blockIdx.x >> 2;   // leaf group (64 leaves)
    const int q     = blockIdx.x & 3;    // k quarter
    const int gl0   = g * 64;
    const int kbase = q * KQ;

    const int lr = lane >> 4;            // row within 4-row group (A staging)
    const int lc = lane & 15;            // 16B chunk within 256B row

    // A staging: wave w, instr j covers rows w*16+j*4..+4, 256B each,
    // source chunk pre-swizzled so LDS-linear dest yields swizzled image.
    const float* pA0;
    const float* pA1;
    const float* pA2;
    const float* pA3;
    {
        const int r0 = wid * 16 + 0 * 4 + lr;
        const int r1 = wid * 16 + 1 * 4 + lr;
        const int r2 = wid * 16 + 2 * 4 + lr;
        const int r3 = wid * 16 + 3 * 4 + lr;
        pA0 = A + (size_t)(gl0 + r0) * SEQ + kbase + (lc ^ (r0 & 7)) * 4;
        pA1 = A + (size_t)(gl0 + r1) * SEQ + kbase + (lc ^ (r1 & 7)) * 4;
        pA2 = A + (size_t)(gl0 + r2) * SEQ + kbase + (lc ^ (r2 & 7)) * 4;
        pA3 = A + (size_t)(gl0 + r3) * SEQ + kbase + (lc ^ (r3 & 7)) * 4;
    }
    // W staging: wave w covers bytes [2w*1024, 2w*1024+2048) of the 8KB image,
    // source is the identical linear image in ws.
    const char* pW = Wt + (size_t)(q * 32) * 8192 + (2 * wid) * 1024 + lane * 16;

    const int fr = lane & 15;
    const int fq = lane >> 4;

    f32x4 acc0 = {0.f, 0.f, 0.f, 0.f};
    f32x4 acc1 = {0.f, 0.f, 0.f, 0.f};
    f32x4 acc2 = {0.f, 0.f, 0.f, 0.f};
    f32x4 acc3 = {0.f, 0.f, 0.f, 0.f};

#define STAGE(bi_) do { \
    char* wdst = (char*)&sW[bi_][0] + 2 * wid * 1024; \
    GLDS16(pW, wdst); \
    GLDS16(pW + 1024, wdst + 1024); \
    pW += 8192; \
    GLDS16(pA0, &sA[bi_][(wid * 16 + 0) * 64]); \
    GLDS16(pA1, &sA[bi_][(wid * 16 + 4) * 64]); \
    GLDS16(pA2, &sA[bi_][(wid * 16 + 8) * 64]); \
    GLDS16(pA3, &sA[bi_][(wid * 16 + 12) * 64]); \
    pA0 += KT; pA1 += KT; pA2 += KT; pA3 += KT; \
} while (0)

#define COMPUTE(bi_) do { \
    const float* bufA_ = &sA[bi_][0]; \
    const char*  bufW_ = &sW[bi_][0]; \
    _Pragma("unroll") \
    for (int k32 = 0; k32 < 2; ++k32) { \
        const u32x4 af = frag_rne(bufA_, wid * 16 + fr, k32 * 32 + fq * 8); \
        const int baddr = fr * 128 + 16 * ((k32 * 4 + fq) ^ (fr & 7)); \
        const u32x4 b0 = *(const u32x4*)(bufW_ + baddr); \
        const u32x4 b1 = *(const u32x4*)(bufW_ + 2048 + baddr); \
        const u32x4 b2 = *(const u32x4*)(bufW_ + 4096 + baddr); \
        const u32x4 b3 = *(const u32x4*)(bufW_ + 6144 + baddr); \
        mfma16(acc0, af, b0); \
        mfma16(acc1, af, b1); \
        mfma16(acc2, af, b2); \
        mfma16(acc3, af, b3); \
    } \
} while (0)

    // prologue: stage tiles 0,1 (12 outstanding glds per wave)
    STAGE(0);
    STAGE(1);

    int bcur = 0, bnxt = 1, bfut = 2;
    #pragma unroll 1
    for (int t = 0; t < NT; ++t) {
        if (t + 1 < NT) asm volatile("s_waitcnt vmcnt(6)" ::: "memory");
        else            asm volatile("s_waitcnt vmcnt(0)" ::: "memory");
        __builtin_amdgcn_s_barrier();
        __builtin_amdgcn_sched_barrier(0);
        if (t + 2 < NT) STAGE(bfut);
        COMPUTE(bcur);
        const int tmp = bcur; bcur = bnxt; bnxt = bfut; bfut = tmp;
    }

#undef STAGE
#undef COMPUTE

    // ---- store partials: wave w rows 16w + fq*4 + r, col n*16 + fr ----
    float* Pq = P + (size_t)q * NLEAF * EMB;
    const int row0 = gl0 + wid * 16 + fq * 4;
    #pragma unroll
    for (int r = 0; r < 4; ++r) {
        Pq[(size_t)(row0 + r) * EMB +  0 + fr] = acc0[r];
        Pq[(size_t)(row0 + r) * EMB + 16 + fr] = acc1[r];
        Pq[(size_t)(row0 + r) * EMB + 32 + fr] = acc2[r];
        Pq[(size_t)(row0 + r) * EMB + 48 + fr] = acc3[r];
    }
}

// ============================================================================
// Tree helpers (fp32 exact). Lane = output dim e; activations broadcast.
// 4 nodes per wave per pass: amortizes the Wt[lane][*] reads x4.
// ============================================================================
__device__ __forceinline__ void load_Wt(float (*Wt)[132],
                                        const float* __restrict__ WW, int tid) {
    const int e  = tid >> 2;
    const int c0 = (tid & 3) * 32;
    #pragma unroll
    for (int j = 0; j < 32; j += 4)
        *(f32x4*)&Wt[e][c0 + j] = *(const f32x4*)&WW[e * 128 + c0 + j];
}

__device__ __forceinline__ float hsum4(const f32x4 a) {
    return a.x + a.y + a.z + a.w;
}

__device__ __forceinline__ float* tree_levels(float* bufA, float* bufB,
        const float (*Wt)[132], float wb, int n0, int nlv, int tid)
{
    const int lane = tid & 63;
    const int wid  = tid >> 6;
    float* src = bufA;
    float* dst = bufB;
    int n = n0;
    for (int lvl = 0; lvl < nlv; ++lvl) {
        const int nodes = n >> 1;
        for (int base = wid * 4; base < nodes; base += 16) {
            const int cnt = (nodes - base < 4) ? (nodes - base) : 4;
            if (cnt == 4) {
                f32x4 ac0 = {0.f,0.f,0.f,0.f}, ac1 = ac0, ac2 = ac0, ac3 = ac0;
                const float* x0 = src + (2 * (base + 0)) * 68;
                const float* x1 = src + (2 * (base + 1)) * 68;
                const float* x2 = src + (2 * (base + 2)) * 68;
                const float* x3 = src + (2 * (base + 3)) * 68;
                #pragma unroll
                for (int j = 0; j < 32; ++j) {
                    const f32x4 w4 = *(const f32x4*)&Wt[lane][4 * j];
                    const int off = (j < 16) ? (4 * j) : (68 + 4 * (j - 16));
                    ac0 += w4 * *(const f32x4*)(x0 + off);
                    ac1 += w4 * *(const f32x4*)(x1 + off);
                    ac2 += w4 * *(const f32x4*)(x2 + off);
                    ac3 += w4 * *(const f32x4*)(x3 + off);
                }
                dst[(base + 0) * 68 + lane] = fmaxf(wb + hsum4(ac0), 0.f);
                dst[(base + 1) * 68 + lane] = fmaxf(wb + hsum4(ac1), 0.f);
                dst[(base + 2) * 68 + lane] = fmaxf(wb + hsum4(ac2), 0.f);
                dst[(base + 3) * 68 + lane] = fmaxf(wb + hsum4(ac3), 0.f);
            } else {
                for (int u = 0; u < cnt; ++u) {
                    f32x4 ac = {0.f, 0.f, 0.f, 0.f};
                    const float* x = src + (2 * (base + u)) * 68;
                    #pragma unroll
                    for (int j = 0; j < 32; ++j) {
                        const f32x4 w4 = *(const f32x4*)&Wt[lane][4 * j];
                        const int off = (j < 16) ? (4 * j) : (68 + 4 * (j - 16));
                        ac += w4 * *(const f32x4*)(x + off);
                    }
                    dst[(base + u) * 68 + lane] = fmaxf(wb + hsum4(ac), 0.f);
                }
            }
        }
        __syncthreads();
        float* tswp = src; src = dst; dst = tswp;
        n = nodes;
    }
    return src;   // root row after final swap
}

// K2: combine 4 K-quarter partials + bias + relu, then tree levels 1..5
// (32 leaves -> 1 root per block). grid 256.
__global__ __launch_bounds__(256) void k_tree32(const float* __restrict__ P,
        const float* __restrict__ eb, const float* __restrict__ WW,
        const float* __restrict__ Wb, float* __restrict__ roots)
{
    __shared__ float hA[32][68];
    __shared__ float hB[16][68];
    __shared__ float Wt[64][132];
    const int tid = threadIdx.x;
    const int b   = blockIdx.x;
    load_Wt(Wt, WW, tid);
    {
        const int lf = tid >> 3;
        const int e0 = (tid & 7) * 8;
        const size_t base = (size_t)(b * 32 + lf) * EMB + e0;
        f32x4 s0 = *(const f32x4*)&P[base];
        f32x4 s1 = *(const f32x4*)&P[base + 4];
        s0 += *(const f32x4*)&P[(size_t)1 * NLEAF * EMB + base];
        s1 += *(const f32x4*)&P[(size_t)1 * NLEAF * EMB + base + 4];
        s0 += *(const f32x4*)&P[(size_t)2 * NLEAF * EMB + base];
        s1 += *(const f32x4*)&P[(size_t)2 * NLEAF * EMB + base + 4];
        s0 += *(const f32x4*)&P[(size_t)3 * NLEAF * EMB + base];
        s1 += *(const f32x4*)&P[(size_t)3 * NLEAF * EMB + base + 4];
        s0 += *(const f32x4*)&eb[e0];
        s1 += *(const f32x4*)&eb[e0 + 4];
        s0.x = fmaxf(s0.x, 0.f); s0.y = fmaxf(s0.y, 0.f);
        s0.z = fmaxf(s0.z, 0.f); s0.w = fmaxf(s0.w, 0.f);
        s1.x = fmaxf(s1.x, 0.f); s1.y = fmaxf(s1.y, 0.f);
        s1.z = fmaxf(s1.z, 0.f); s1.w = fmaxf(s1.w, 0.f);
        *(f32x4*)&hA[lf][e0]     = s0;
        *(f32x4*)&hA[lf][e0 + 4] = s1;
    }
    const float wb = Wb[tid & 63];
    __syncthreads();
    float* root = tree_levels(&hA[0][0], &hB[0][0], Wt, wb, 32, 5, tid);
    if (tid < 64) roots[b * 64 + tid] = root[tid];
}

// K3a: 16 roots -> 1 (levels 6..9). grid 16.
__global__ __launch_bounds__(256) void k_tree16(const float* __restrict__ in,
        const float* __restrict__ WW, const float* __restrict__ Wb,
        float* __restrict__ outv)
{
    __shared__ float hA[32][68];
    __shared__ float hB[16][68];
    __shared__ float Wt[64][132];
    const int tid = threadIdx.x;
    load_Wt(Wt, WW, tid);
    {
        const int r  = tid >> 4;
        const int e0 = (tid & 15) * 4;
        *(f32x4*)&hA[r][e0] =
            *(const f32x4*)&in[(size_t)(blockIdx.x * 16 + r) * EMB + e0];
    }
    const float wb = Wb[tid & 63];
    __syncthreads();
    float* root = tree_levels(&hA[0][0], &hB[0][0], Wt, wb, 16, 4, tid);
    if (tid < 64) outv[blockIdx.x * 64 + tid] = root[tid];
}

// K3b: 16 -> 1 (levels 10..13) + projection. grid 1.
__global__ __launch_bounds__(256) void k_root(const float* __restrict__ in,
        const float* __restrict__ WW, const float* __restrict__ Wb,
        const float* __restrict__ pW, const float* __restrict__ pb,
        float* __restrict__ out)
{
    __shared__ float hA[32][68];
    __shared__ float hB[16][68];
    __shared__ float Wt[64][132];
    const int tid = threadIdx.x;
    load_Wt(Wt, WW, tid);
    {
        const int r  = tid >> 4;
        const int e0 = (tid & 15) * 4;
        *(f32x4*)&hA[r][e0] = *(const f32x4*)&in[(size_t)r * EMB + e0];
    }
    const float wb = Wb[tid & 63];
    __syncthreads();
    float* root = tree_levels(&hA[0][0], &hB[0][0], Wt, wb, 16, 4, tid);
    if (tid < 64) {
        const float hv = root[tid];
        float t0 = hv * pW[tid];
        float t1 = hv * pW[64 + tid];
        #pragma unroll
        for (int off = 32; off > 0; off >>= 1) {
            t0 += __shfl_down(t0, off);
            t1 += __shfl_down(t1, off);
        }
        if (tid == 0) { out[0] = t0 + pb[0]; out[1] = t1 + pb[1]; }
    }
}

extern "C" void kernel_launch(void* const* d_in, const int* in_sizes, int n_in,
                              void* d_out, int out_size, void* d_ws, size_t ws_size,
                              hipStream_t stream)
{
    const float* A  = (const float*)d_in[0];   // leaf_seqs [8192][8192]
    const float* eW = (const float*)d_in[1];   // emb_W     [64][8192]
    const float* eb = (const float*)d_in[2];   // emb_b     [64]
    const float* WW = (const float*)d_in[3];   // W_W       [64][128]
    const float* Wb = (const float*)d_in[4];   // W_b       [64]
    const float* pW = (const float*)d_in[5];   // proj_W    [2][64]
    const float* pb = (const float*)d_in[6];   // proj_b    [2]
    float* out = (float*)d_out;

    float* P     = (float*)d_ws;                       // [4][8192][64] f32 = 8MB
    float* roots = P + (size_t)4 * NLEAF * EMB;        // [256][64]
    float* l9    = roots + 256 * EMB;                  // [16][64]
    char*  Wtil  = (char*)d_ws + (size_t)16 * 1024 * 1024;  // 1MB bf16 tile imgs

    k_cvtW  <<<dim3(256), dim3(256), 0, stream>>>(eW, (unsigned*)Wtil);
    k_gemm  <<<dim3(512), dim3(256), 0, stream>>>(A, Wtil, P);
    k_tree32<<<dim3(256), dim3(256), 0, stream>>>(P, eb, WW, Wb, roots);
    k_tree16<<<dim3(16),  dim3(256), 0, stream>>>(roots, WW, Wb, l9);
    k_root  <<<dim3(1),   dim3(256), 0, stream>>>(l9, WW, Wb, pW, pb, out);
}